// Round 10
// baseline (45.404 us; speedup 1.0000x reference)
//
#include <hip/hip_runtime.h>

typedef _Float16 h2 __attribute__((ext_vector_type(2)));

#define IH 512
#define IW 512
#define OH 502
#define OW 502
#define NIMG 48
#define ROWS 32
#define NSTRIP 16                 // 16*32 = 512 >= 502
#define NBLK (NSTRIP * NIMG)      // 768
#define PADW 524                  // h2 words per rowbuf row; 524*4B = 2096 % 16 == 0
#define LASTS 20                  // pair-steps S = 0..20 (42 input rows)
#define C1V 1.0e-4f
#define C2V 9.0e-4f

// gaussian(win=11, sigma=1.5), normalized
constexpr float GFc[11] = {
    0.00102838f, 0.00759876f, 0.03600078f, 0.10936070f, 0.21300554f,
    0.26601173f, 0.21300554f, 0.10936070f, 0.03600078f, 0.00759876f,
    0.00102838f};

// cvt_pkrtz returns __fp16-vec; bit-cast to our _Float16-vec h2 (same layout)
static __device__ __forceinline__ h2 pkrtz(float a, float b) {
    return __builtin_bit_cast(h2, __builtin_amdgcn_cvt_pkrtz(a, b));
}

// force a packed-f16 constant into an SGPR (VOP3P has no packed literals;
// v_pk_* legally take 1 SGPR source -> no per-use remat, -VGPR)
static __device__ __forceinline__ h2 sgpr_h2(float a, float b) {
    h2 v = h2{(_Float16)a, (_Float16)b};
    int i = __builtin_amdgcn_readfirstlane(__builtin_bit_cast(int, v));
    return __builtin_bit_cast(h2, i);
}

struct SC { h2 c1, c2, two, one; };   // SGPR-resident h2 constants

struct Pre {  // pipelined loads for one pair-step
    float a2, a3;   // yt col c,   rows 2X+1, 2X+2
    float b2, b3;   // yt col c-1, rows 2X+1, 2X+2
    float d2, d3;   // yt col c+1, rows 2X+1, 2X+2
    float e0, e1;   // yp col c,   rows 2X,   2X+1
};

template <int M>
__device__ __forceinline__ Pre& pick(Pre& A, Pre& B) {
    if constexpr (M == 0) return A;
    else return B;
}

struct __align__(16) H4  { h2 a, b, c, d; };
struct __align__(8)  H22 { h2 x, y; };

// 8-row H-phase: thread -> (row-pair rp = tid>>7, out cols cb..cb+3).
// 14 aligned words per q (3x b128 + 1x b64); packed 11-tap blur; packed SSIM
// with branchless mask folding; f32 only for the final rcp+accumulate.
__device__ __forceinline__ void hphase8(const h2 (*rb)[5][PADW], int orow0,
                                        int tid, const h2 (&gh)[11], const SC& sc,
                                        float& lsum) {
    const int rp = tid >> 7;             // pair-slot 0..3
    const int cb = (tid & 127) << 2;     // out-col base 0..508 (16B aligned)
    h2 ov[5][4];                         // packed (row-even, row-odd) per q, col
#pragma unroll
    for (int q = 0; q < 5; q++) {
        const h2* rowp = &rb[rp][q][cb];
        H4  t0 = *(const H4*)(rowp);
        H4  t1 = *(const H4*)(rowp + 4);
        H4  t2 = *(const H4*)(rowp + 8);
        H22 t3 = *(const H22*)(rowp + 12);
        h2 w[14] = {t0.a, t0.b, t0.c, t0.d, t1.a, t1.b, t1.c, t1.d,
                    t2.a, t2.b, t2.c, t2.d, t3.x, t3.y};
#pragma unroll
        for (int j = 0; j < 4; j++) {
            h2 s = gh[0] * w[j];
#pragma unroll
            for (int k = 1; k < 11; k++) s += gh[k] * w[j + k];
            ov[q][j] = s;
        }
    }
    const int gr0 = orow0 + (rp << 1);
    const h2 zero = h2{(_Float16)0.f, (_Float16)0.f};
    const h2 mrow = pkrtz(gr0 < OH ? 1.f : 0.f, gr0 + 1 < OH ? 1.f : 0.f);
#pragma unroll
    for (int j = 0; j < 4; j++) {
        const h2 mk = (cb + j < OW) ? mrow : zero;
        const h2 iv = sc.one - mk;
        h2 mu1 = ov[0][j], mu2 = ov[1][j];
        h2 exx = ov[2][j], eyy = ov[3][j], exy = ov[4][j];
        h2 mu1s = mu1 * mu1, mu2s = mu2 * mu2, mu12 = mu1 * mu2;
        h2 s1v = exx - mu1s, s2v = eyy - mu2s, s12 = exy - mu12;
        h2 num = (mu12 * sc.two + sc.c1) * (s12 * sc.two + sc.c2);
        h2 den = (mu1s + mu2s + sc.c1) * (s1v + s2v + sc.c2);
        num = num * mk;
        den = den * mk + iv;          // masked lanes: den=1, num=0 (no inf/NaN)
        float nlo = (float)num.x, nhi = (float)num.y;
        float dlo = (float)den.x, dhi = (float)den.y;
        lsum += nlo * __builtin_amdgcn_rcpf(dlo);
        lsum += nhi * __builtin_amdgcn_rcpf(dhi);
    }
}

// one pair-step: input rows ir = O0+2S, ir+1 (depth-2 prefetch, in-place buffer)
// V-ring packed by OUTPUT-ROW PAIRS: acc2[p%6][q] = (out_{2p}, out_{2p+1}) in h2.
template <int S>
__device__ __forceinline__ void stepf(
    h2 (&acc2)[6][5], float& a0, float& a1, float& b1, float& d1,
    Pre& preA, Pre& preB,
    const float* __restrict__ ytb, const float* __restrict__ ypb,
    int O0, int c, int cm, int cp, bool cgt0, bool clt511,
    const h2 (&wA)[6], const h2 (&wB)[6], const h2 (&gh)[11], const SC& sc,
    h2 (*rbuf)[5][PADW], int tid, float& lsum) {
    Pre& cur = pick<S % 2>(preA, preB);
    // ---- consume cur first (reference, no copy): edge-enhance rows ir, ir+1 ----
    float lf0 = cgt0 ? b1 : 0.f;
    float rt0 = clt511 ? d1 : 0.f;
    float lf1 = cgt0 ? cur.b2 : 0.f;
    float rt1 = clt511 ? cur.d2 : 0.f;
    float xr0 = a0 + cur.a2 + lf0 + rt0 - 4.f * a1;
    float xr1 = a1 + cur.a3 + lf1 + rt1 - 4.f * cur.a2;
    float pr0[5] = {xr0, cur.e0, xr0 * xr0, cur.e0 * cur.e0, xr0 * cur.e0};
    float pr1[5] = {xr1, cur.e1, xr1 * xr1, cur.e1 * cur.e1, xr1 * cur.e1};
    h2 bc0[5], bc1[5];   // row-broadcast packs
#pragma unroll
    for (int q = 0; q < 5; q++) {
        bc0[q] = pkrtz(pr0[q], pr0[q]);
        bc1[q] = pkrtz(pr1[q], pr1[q]);
    }
    // carries (all cur reads complete before the buffer is reused)
    a0 = cur.a2; a1 = cur.a3; b1 = cur.b3; d1 = cur.d3;
    // ---- issue loads for step S+2 into cur (uniform row ptrs -> SALU addr) ----
    if constexpr (S + 2 <= LASTS) {
        const int r1 = min(O0 + 2 * S + 5, IH - 1);
        const int r2 = min(O0 + 2 * S + 6, IH - 1);
        const int rE = min(O0 + 2 * S + 4, IH - 1);
        const float* pr1p = ytb + (size_t)r1 * IW;
        const float* pr2p = ytb + (size_t)r2 * IW;
        const float* pe0p = ypb + (size_t)rE * IW;
        const float* pe1p = ypb + (size_t)r1 * IW;
        cur.a2 = pr1p[c];  cur.a3 = pr2p[c];
        cur.b2 = pr1p[cm]; cur.b3 = pr2p[cm];
        cur.d2 = pr1p[cp]; cur.d3 = pr2p[cp];
        cur.e0 = pe0p[c];  cur.e1 = pe1p[c];
    }
    // ---- packed V-ring: live output pairs p = S-5..S (clipped to [0,15]) ----
    // out_{2p}   += g[2i]  *v_r + g[2i+1]*v_r1      (i = S-p)
    // out_{2p+1} += g[2i-1]*v_r + g[2i]  *v_r1
    // => acc2[p%6] += wA[i] (*) bc0 + wB[i] (*) bc1   (2x v_pk_fma_f16)
    constexpr int PLO = (S - 5 < 0) ? 0 : (S - 5);
    constexpr int PHI = (S > 15) ? 15 : S;
#pragma unroll
    for (int p = PLO; p <= PHI; ++p) {
        const int i = S - p;          // 0..5, constant after unroll
        const int sl = p % 6;
#pragma unroll
        for (int q = 0; q < 5; q++) {
            if (i == 0) {
                acc2[sl][q] = wA[0] * bc0[q];               // y-half: 0 (fresh)
                acc2[sl][q] = wB[0] * bc1[q] + acc2[sl][q];
            } else {
                acc2[sl][q] = wA[i] * bc0[q] + acc2[sl][q];
                acc2[sl][q] = wB[i] * bc1[q] + acc2[sl][q];
            }
        }
    }
    // ---- emit completed pair p = S-5 (already packed h2): direct store ----
    if constexpr (S >= 5) {
        constexpr int p = S - 5;
        constexpr int sl = p % 6;
        constexpr int sl2 = p & 3;           // slot within 8-row phase
#pragma unroll
        for (int q = 0; q < 5; q++)
            rbuf[sl2][q][c] = acc2[sl][q];
    }
    // ---- 8-row phase at S = 8,12,16,20 (lgkm-only barriers; vmcnt in flight) ----
    if constexpr (S >= 8 && ((S - 8) % 4) == 0) {
        asm volatile("s_waitcnt lgkmcnt(0)\n\ts_barrier" ::: "memory");
        hphase8(rbuf, O0 + 8 * ((S - 8) / 4), tid, gh, sc, lsum);
        if constexpr (S < LASTS)   // protect slot reuse by next emits
            asm volatile("s_waitcnt lgkmcnt(0)\n\ts_barrier" ::: "memory");
    }
}

template <int S, typename... A>
__device__ __forceinline__ void run_steps(A&... a) {
    stepf<S>(a...);
    if constexpr (S < LASTS) run_steps<S + 1>(a...);
}

__global__ __launch_bounds__(512) void ssim_stream(const float* __restrict__ yt,
                                                   const float* __restrict__ yp,
                                                   float* __restrict__ partial) {
    __shared__ __align__(16) h2 rbuf[4][5][PADW];   // ~41.9 KB, single-buffered
    __shared__ float wred[8];

    const int tid = threadIdx.x;
    const int c = tid;
    const int strip = blockIdx.x;
    const int img = blockIdx.y;
    const int O0 = strip * ROWS;
    const size_t ib = (size_t)img * (IH * IW);
    const float* ytb = yt + ib;
    const float* ypb = yp + ib;

    const int cm = c > 0 ? c - 1 : 0;
    const int cp = c < (IW - 1) ? c + 1 : (IW - 1);
    const bool cgt0 = c > 0, clt511 = c < (IW - 1);

    // zero the halo words 512..523 (read by cb>=500 threads, never emitted)
    if (tid < 240) {
        int sl = tid / 60, rem = tid % 60;
        int q = rem / 12, w = 512 + rem % 12;
        rbuf[sl][q][w] = h2{(_Float16)0.f, (_Float16)0.f};
    }

    // weights + constants in SGPRs (1 SGPR src legal for v_pk_*)
    // wA[i] = (g[2i], g[2i-1]) with g[-1]=0; wB[i] = (g[2i+1], g[2i]) with g[11]=0
    h2 wA[6], wB[6], gh[11];
    wA[0] = sgpr_h2(GFc[0], 0.f);
#pragma unroll
    for (int i = 1; i < 6; i++) wA[i] = sgpr_h2(GFc[2 * i], GFc[2 * i - 1]);
#pragma unroll
    for (int i = 0; i < 5; i++) wB[i] = sgpr_h2(GFc[2 * i + 1], GFc[2 * i]);
    wB[5] = sgpr_h2(0.f, GFc[10]);
#pragma unroll
    for (int k = 0; k < 11; k++) gh[k] = sgpr_h2(GFc[k], GFc[k]);
    const SC sc = {sgpr_h2(C1V, C1V), sgpr_h2(C2V, C2V),
                   sgpr_h2(2.f, 2.f), sgpr_h2(1.f, 1.f)};

    // prologue: carries + first TWO steps' loads (uniform row pointers)
    float a0, a1, b1, d1;
    {
        const int rm1 = O0 > 0 ? O0 - 1 : 0;
        const float* pm1 = ytb + (size_t)rm1 * IW;
        const float* p0  = ytb + (size_t)O0 * IW;
        float a0v = pm1[c];
        a1 = p0[c]; b1 = p0[cm]; d1 = p0[cp];
        a0 = (O0 > 0) ? a0v : 0.f;
    }
    Pre preA, preB;
    auto fill = [&](Pre& dst, int X) {
        const int r1 = min(O0 + 2 * X + 1, IH - 1);
        const int r2 = min(O0 + 2 * X + 2, IH - 1);
        const int rE = min(O0 + 2 * X,     IH - 1);
        const float* pr1p = ytb + (size_t)r1 * IW;
        const float* pr2p = ytb + (size_t)r2 * IW;
        const float* pe0p = ypb + (size_t)rE * IW;
        const float* pe1p = ypb + (size_t)r1 * IW;
        dst.a2 = pr1p[c];  dst.a3 = pr2p[c];
        dst.b2 = pr1p[cm]; dst.b3 = pr2p[cm];
        dst.d2 = pr1p[cp]; dst.d3 = pr2p[cp];
        dst.e0 = pe0p[c];  dst.e1 = pe1p[c];
    };
    fill(preA, 0);
    fill(preB, 1);

    h2 acc2[6][5];   // packed ring; every slot is init-on-first-tap (i==0 mul)
    float lsum = 0.f;

    run_steps<0>(acc2, a0, a1, b1, d1, preA, preB, ytb, ypb, O0,
                 c, cm, cp, cgt0, clt511, wA, wB, gh, sc, rbuf, tid, lsum);

#pragma unroll
    for (int off = 32; off > 0; off >>= 1) lsum += __shfl_down(lsum, off);
    if ((tid & 63) == 0) wred[tid >> 6] = lsum;
    __syncthreads();
    if (tid == 0) {
        float s = 0.f;
#pragma unroll
        for (int w = 0; w < 8; w++) s += wred[w];
        partial[strip + NSTRIP * img] = s;
    }
}

__global__ __launch_bounds__(256) void ssim_final(const float* __restrict__ partial,
                                                  float* __restrict__ out) {
    __shared__ double wred[4];
    double s = 0.0;
    for (int i = threadIdx.x; i < NBLK; i += 256) s += (double)partial[i];
#pragma unroll
    for (int off = 32; off > 0; off >>= 1) s += __shfl_down(s, off);
    if ((threadIdx.x & 63) == 0) wred[threadIdx.x >> 6] = s;
    __syncthreads();
    if (threadIdx.x == 0) {
        double tot = wred[0] + wred[1] + wred[2] + wred[3];
        out[0] = (float)(1.0 - tot / (double)((long long)OH * OW * NIMG));
    }
}

extern "C" void kernel_launch(void* const* d_in, const int* in_sizes, int n_in,
                              void* d_out, int out_size, void* d_ws, size_t ws_size,
                              hipStream_t stream) {
    const float* yt = (const float*)d_in[0];
    const float* yp = (const float*)d_in[1];
    float* out = (float*)d_out;
    float* partial = (float*)d_ws;   // NBLK floats = 3 KB

    dim3 grid(NSTRIP, NIMG);
    hipLaunchKernelGGL(ssim_stream, grid, dim3(512), 0, stream, yt, yp, partial);
    hipLaunchKernelGGL(ssim_final, dim3(1), dim3(256), 0, stream, partial, out);
}